// Round 13
// baseline (255.996 us; speedup 1.0000x reference)
//
#include <hip/hip_runtime.h>
#include <hip/hip_bf16.h>

#define DD 128
#define RR 8
#define KK 1152      // RGCN composite K = 128 + 8*128
#define SCAN_CHUNK 2048
#define KSPLIT 8
#define KP 4096      // padded sim K

typedef _Float16 h8 __attribute__((ext_vector_type(8)));
typedef _Float16 h4 __attribute__((ext_vector_type(4)));
typedef float f4 __attribute__((ext_vector_type(4)));

__device__ __forceinline__ void gload16(const _Float16* g, _Float16* l) {
  __builtin_amdgcn_global_load_lds(
      (const __attribute__((address_space(1))) void*)g,
      (__attribute__((address_space(3))) void*)l, 16, 0, 0);
}

// ---------------- packed 16-bit count: 2 (dst,rel) bins per word ----------
__global__ __launch_bounds__(256) void count_k(const int* __restrict__ edst,
    const int* __restrict__ etyp, unsigned* __restrict__ cntp, int E) {
  int i = blockIdx.x * 256 + threadIdx.x;
  if (i < E) {
    int seg = edst[i] * RR + etyp[i];
    atomicAdd(&cntp[seg >> 1], 1u << ((seg & 1) << 4));
  }
}

// ---------------- 3-phase exclusive scan of packed cnt -> off -------------
__global__ __launch_bounds__(256) void scan_a(const unsigned* __restrict__ cntp,
    int* __restrict__ off, int* __restrict__ bsum, int n) {
  __shared__ int red[256];
  int base = blockIdx.x * SCAN_CHUNK + threadIdx.x * 8;
  int v[8];
  int s = 0;
#pragma unroll
  for (int i = 0; i < 8; ++i) {
    int idx = base + i;
    v[i] = s;
    int c = 0;
    if (idx < n) {
      unsigned word = cntp[idx >> 1];
      c = (word >> ((idx & 1) << 4)) & 0xFFFF;
    }
    s += c;
  }
  red[threadIdx.x] = s;
  __syncthreads();
  for (int o = 1; o < 256; o <<= 1) {
    int t = (threadIdx.x >= o) ? red[threadIdx.x - o] : 0;
    __syncthreads();
    red[threadIdx.x] += t;
    __syncthreads();
  }
  int pre = (threadIdx.x > 0) ? red[threadIdx.x - 1] : 0;
#pragma unroll
  for (int i = 0; i < 8; ++i) {
    int idx = base + i;
    if (idx < n) off[idx] = v[i] + pre;
  }
  if (threadIdx.x == 255) bsum[blockIdx.x] = red[255];
}

__global__ void scan_b(int* __restrict__ bsum, int nb) {
  if (threadIdx.x == 0) {
    int s = 0;
    for (int i = 0; i < nb; ++i) { int t = bsum[i]; bsum[i] = s; s += t; }
  }
}

// scan_c also materializes cur (= off copy)
__global__ __launch_bounds__(256) void scan_c(int* __restrict__ off,
    const int* __restrict__ bsum, int* __restrict__ cur, int n) {
  int i = blockIdx.x * 256 + threadIdx.x;
  if (i < n) {
    int v = off[i] + bsum[i >> 11];
    off[i] = v;
    cur[i] = v;
  }
}

// ---------------- fill CSR ----------------
__global__ __launch_bounds__(256) void fill_k(const int* __restrict__ esrc,
    const int* __restrict__ edst, const int* __restrict__ etyp,
    int* __restrict__ cur, int* __restrict__ eidx, int E) {
  int e = blockIdx.x * 256 + threadIdx.x;
  if (e < E) {
    int seg = edst[e] * RR + etyp[e];
    int p = atomicAdd(&cur[seg], 1);
    eidx[p] = esrc[e];
  }
}

// ---------------- maskf scatter: maskf[mri[i]] = 1 ----------------
__global__ __launch_bounds__(256) void maskset_k(const int* __restrict__ mri,
    float* __restrict__ maskf, int nd) {
  int i = blockIdx.x * 256 + threadIdx.x;
  if (i < nd) maskf[mri[i]] = 1.0f;
}

// ---------------- sim row convert + fused rowsum (body) ----------------
__device__ __forceinline__ void convsim_body(const float* __restrict__ sim,
    const int* __restrict__ mri, const float* __restrict__ maskf,
    _Float16* __restrict__ simh, float* __restrict__ rs, int nd, int i,
    float* red) {
  const float* row = sim + (size_t)mri[i] * nd;
  float acc = 0.f;
  for (int c4 = threadIdx.x; c4 < KP / 4; c4 += 256) {
    int c = c4 * 4;
    float4 v = make_float4(0.f, 0.f, 0.f, 0.f);
    if (c < nd) {
      v = *(const float4*)(row + c);
      float4 mk = *(const float4*)(maskf + c);
      acc += v.x * mk.x + v.y * mk.y + v.z * mk.z + v.w * mk.w;
    }
    h4 o = {(_Float16)v.x, (_Float16)v.y, (_Float16)v.z, (_Float16)v.w};
    *(h4*)(simh + (size_t)i * KP + c) = o;
  }
  red[threadIdx.x] = acc;
  __syncthreads();
  for (int o = 128; o > 0; o >>= 1) {
    if (threadIdx.x < o) red[threadIdx.x] += red[threadIdx.x + o];
    __syncthreads();
  }
  if (threadIdx.x == 0) rs[i] = red[0] + 1e-9f;
}

// ---------------- transposed f16 weights via LDS tile (body) ----------------
__device__ __forceinline__ void convwT_body(const float* __restrict__ Ws,
    const float* __restrict__ Wr, _Float16* __restrict__ WT, int bid,
    _Float16 (*tile)[72]) {
  const int k0 = (bid % (KK / 64)) * 64, n0 = (bid / (KK / 64)) * 64;
  const int t = threadIdx.x;
  {
    int kr = t >> 2, c0 = (t & 3) * 16;
    int k = k0 + kr;
    const float* src = (k < DD) ? (Ws + (size_t)k * DD + n0 + c0)
                                : (Wr + (size_t)(k - DD) * DD + n0 + c0);
#pragma unroll
    for (int j = 0; j < 16; j += 4) {
      float4 v = *(const float4*)(src + j);
      tile[kr][c0 + j + 0] = (_Float16)v.x;
      tile[kr][c0 + j + 1] = (_Float16)v.y;
      tile[kr][c0 + j + 2] = (_Float16)v.z;
      tile[kr][c0 + j + 3] = (_Float16)v.w;
    }
  }
  __syncthreads();
  {
    int nr = t >> 2, ck = (t & 3) * 16;
    h8 o0, o1;
#pragma unroll
    for (int j = 0; j < 8; ++j) {
      o0[j] = tile[ck + j][nr];
      o1[j] = tile[ck + 8 + j][nr];
    }
    *(h8*)(WT + (size_t)(n0 + nr) * KK + k0 + ck) = o0;
    *(h8*)(WT + (size_t)(n0 + nr) * KK + k0 + ck + 8) = o1;
  }
}

// ---------------- streaming prep: convsim | convx | convwT x2 -------------
__global__ __launch_bounds__(256) void stream_k(
    const float* __restrict__ sim, const int* __restrict__ mri,
    const float* __restrict__ maskf, _Float16* __restrict__ simh,
    float* __restrict__ rs, int nd,
    const float* __restrict__ x, _Float16* __restrict__ xh, int n4x,
    const float* __restrict__ W1s, const float* __restrict__ W1r,
    _Float16* __restrict__ WT1,
    const float* __restrict__ W2s, const float* __restrict__ W2r,
    _Float16* __restrict__ WT2, int bX, int bW) {
  __shared__ char smem[64 * 72 * 2];
  const int b = blockIdx.x, t = threadIdx.x;
  if (b < nd) {
    convsim_body(sim, mri, maskf, simh, rs, nd, b, (float*)smem);
    return;
  }
  int b2 = b - nd;
  if (b2 < bX) {
    int i = b2 * 256 + t;
    if (i < n4x) {
      float4 v = *(const float4*)(x + (size_t)i * 4);
      h4 o = {(_Float16)v.x, (_Float16)v.y, (_Float16)v.z, (_Float16)v.w};
      *(h4*)(xh + (size_t)i * 4) = o;
    }
    return;
  }
  b2 -= bX;
  if (b2 < bW) {
    convwT_body(W1s, W1r, WT1, b2, (_Float16(*)[72])smem);
    return;
  }
  b2 -= bW;
  convwT_body(W2s, W2r, WT2, b2, (_Float16(*)[72])smem);
}

// ---------------- aggregation: 2 segments/thread, 8-deep load pipeline ----
__device__ __forceinline__ void agg_body2(const _Float16* __restrict__ h,
    const int* __restrict__ off, const int* __restrict__ eidx,
    _Float16* __restrict__ msg, int nseg, int E, int gid) {
  int pr = gid >> 4, q = gid & 15;
  int sg = pr * 2;
  if (sg >= nseg) return;
  int b0 = off[sg];
  int b1 = (sg + 1 < nseg) ? off[sg + 1] : E;
  int e1 = (sg + 2 < nseg) ? off[sg + 2] : E;
  int n0 = b1 - b0, n1 = e1 - b1;
  int eL = E - 1;
  int i00 = eidx[min(b0 + 0, eL)];
  int i01 = eidx[min(b0 + 1, eL)];
  int i02 = eidx[min(b0 + 2, eL)];
  int i03 = eidx[min(b0 + 3, eL)];
  int i10 = eidx[min(b1 + 0, eL)];
  int i11 = eidx[min(b1 + 1, eL)];
  int i12 = eidx[min(b1 + 2, eL)];
  int i13 = eidx[min(b1 + 3, eL)];
  h8 v00 = *(const h8*)(h + (size_t)i00 * DD + q * 8);
  h8 v01 = *(const h8*)(h + (size_t)i01 * DD + q * 8);
  h8 v02 = *(const h8*)(h + (size_t)i02 * DD + q * 8);
  h8 v03 = *(const h8*)(h + (size_t)i03 * DD + q * 8);
  h8 v10 = *(const h8*)(h + (size_t)i10 * DD + q * 8);
  h8 v11 = *(const h8*)(h + (size_t)i11 * DD + q * 8);
  h8 v12 = *(const h8*)(h + (size_t)i12 * DD + q * 8);
  h8 v13 = *(const h8*)(h + (size_t)i13 * DD + q * 8);
  float a0[8], a1[8];
#pragma unroll
  for (int j = 0; j < 8; ++j) { a0[j] = 0.f; a1[j] = 0.f; }
  if (n0 > 0) {
#pragma unroll
    for (int j = 0; j < 8; ++j) a0[j] = (float)v00[j];
    if (n0 > 1) {
#pragma unroll
      for (int j = 0; j < 8; ++j) a0[j] += (float)v01[j];
    }
    if (n0 > 2) {
#pragma unroll
      for (int j = 0; j < 8; ++j) a0[j] += (float)v02[j];
    }
    if (n0 > 3) {
#pragma unroll
      for (int j = 0; j < 8; ++j) a0[j] += (float)v03[j];
    }
    for (int i = b0 + 4; i < b1; ++i) {
      int s = eidx[i];
      h8 v = *(const h8*)(h + (size_t)s * DD + q * 8);
#pragma unroll
      for (int j = 0; j < 8; ++j) a0[j] += (float)v[j];
    }
  }
  if (n1 > 0) {
#pragma unroll
    for (int j = 0; j < 8; ++j) a1[j] = (float)v10[j];
    if (n1 > 1) {
#pragma unroll
      for (int j = 0; j < 8; ++j) a1[j] += (float)v11[j];
    }
    if (n1 > 2) {
#pragma unroll
      for (int j = 0; j < 8; ++j) a1[j] += (float)v12[j];
    }
    if (n1 > 3) {
#pragma unroll
      for (int j = 0; j < 8; ++j) a1[j] += (float)v13[j];
    }
    for (int i = b1 + 4; i < e1; ++i) {
      int s = eidx[i];
      h8 v = *(const h8*)(h + (size_t)s * DD + q * 8);
#pragma unroll
      for (int j = 0; j < 8; ++j) a1[j] += (float)v[j];
    }
  }
  float ic0 = (n0 > 0) ? 1.0f / (float)n0 : 0.0f;
  float ic1 = (n1 > 0) ? 1.0f / (float)n1 : 0.0f;
  h8 o0, o1;
#pragma unroll
  for (int j = 0; j < 8; ++j) {
    o0[j] = (_Float16)(a0[j] * ic0);
    o1[j] = (_Float16)(a1[j] * ic1);
  }
  *(h8*)(msg + (size_t)sg * DD + q * 8) = o0;
  if (sg + 1 < nseg)
    *(h8*)(msg + (size_t)(sg + 1) * DD + q * 8) = o1;
}

__global__ __launch_bounds__(256) void agg_k(const _Float16* __restrict__ h,
    const int* __restrict__ off, const int* __restrict__ eidx,
    _Float16* __restrict__ msg, int nseg, int E) {
  agg_body2(h, off, eidx, msg, nseg, E, blockIdx.x * 256 + threadIdx.x);
}

// ---------------- MFMA RGCN GEMM: out = [xh | msg] @ WT^T ----------------
template <bool RELU, bool F16OUT>
__global__ __launch_bounds__(256) void rgcn_mfma(const _Float16* __restrict__ xh,
    const _Float16* __restrict__ msg, const _Float16* __restrict__ WT,
    void* __restrict__ outv, int nN) {
  __shared__ _Float16 Ab[2][64 * 64];
  __shared__ _Float16 Bb[2][128 * 64];
  const int t = threadIdx.x;
  const int lane = t & 63, w = t >> 6;
  const int row0 = blockIdx.x * 64;
  const int wm = w >> 1, wn = w & 1;
  const int lr = lane & 15, lg = lane >> 4;

  f4 acc[2][4];
#pragma unroll
  for (int mi = 0; mi < 2; ++mi)
#pragma unroll
    for (int ni = 0; ni < 4; ++ni) acc[mi][ni] = (f4){0.f, 0.f, 0.f, 0.f};

  const _Float16* pxh[2];
  const _Float16* pmsg[2];
  int ldsA[2];
#pragma unroll
  for (int j = 0; j < 2; ++j) {
    int q = j * 256 + w * 64 + lane;
    int row = q >> 3;
    int gck = (q & 7) ^ (row & 7);
    int m = row0 + row; if (m >= nN) m = nN - 1;
    pxh[j] = xh + (size_t)m * DD + gck * 8;
    pmsg[j] = msg + (size_t)m * (RR * DD) + gck * 8;
    ldsA[j] = (j * 256 + w * 64) * 8;
  }
  const _Float16* pB[4];
  int ldsB[4];
#pragma unroll
  for (int i = 0; i < 4; ++i) {
    int q = i * 256 + w * 64 + lane;
    int n = q >> 3;
    int gck = (q & 7) ^ (n & 7);
    pB[i] = WT + (size_t)n * KK + gck * 8;
    ldsB[i] = (i * 256 + w * 64) * 8;
  }

  const int nsteps = KK / 64;  // 18
#pragma unroll
  for (int j = 0; j < 2; ++j) gload16(pxh[j], &Ab[0][ldsA[j]]);
#pragma unroll
  for (int i = 0; i < 4; ++i) gload16(pB[i], &Bb[0][ldsB[i]]);
  asm volatile("s_waitcnt vmcnt(0)" ::: "memory");
  __syncthreads();

  for (int ts = 0; ts < nsteps; ++ts) {
    const int cur = ts & 1;
    if (ts + 1 < nsteps) {
      const int kk = (ts + 1) * 64;
      const int nxt = cur ^ 1;
      if (kk < DD) {
#pragma unroll
        for (int j = 0; j < 2; ++j) gload16(pxh[j] + kk, &Ab[nxt][ldsA[j]]);
      } else {
#pragma unroll
        for (int j = 0; j < 2; ++j) gload16(pmsg[j] + (kk - DD), &Ab[nxt][ldsA[j]]);
      }
#pragma unroll
      for (int i = 0; i < 4; ++i) gload16(pB[i] + kk, &Bb[nxt][ldsB[i]]);
    }
#pragma unroll
    for (int s = 0; s < 2; ++s) {
      h8 af[2], bf[4];
#pragma unroll
      for (int mi = 0; mi < 2; ++mi) {
        int r = wm * 32 + mi * 16 + lr;
        af[mi] = *(const h8*)&Ab[cur][r * 64 + (((s * 4 + lg) ^ (r & 7)) << 3)];
      }
#pragma unroll
      for (int ni = 0; ni < 4; ++ni) {
        int n = wn * 64 + ni * 16 + lr;
        bf[ni] = *(const h8*)&Bb[cur][n * 64 + (((s * 4 + lg) ^ (n & 7)) << 3)];
      }
#pragma unroll
      for (int mi = 0; mi < 2; ++mi)
#pragma unroll
        for (int ni = 0; ni < 4; ++ni)
          acc[mi][ni] = __builtin_amdgcn_mfma_f32_16x16x32_f16(
              af[mi], bf[ni], acc[mi][ni], 0, 0, 0);
    }
    asm volatile("s_waitcnt vmcnt(0)" ::: "memory");
    __syncthreads();
  }

#pragma unroll
  for (int mi = 0; mi < 2; ++mi) {
#pragma unroll
    for (int j = 0; j < 4; ++j) {
      int row = row0 + wm * 32 + mi * 16 + lg * 4 + j;
      if (row < nN) {
#pragma unroll
        for (int ni = 0; ni < 4; ++ni) {
          int col = wn * 64 + ni * 16 + lr;
          float v = acc[mi][ni][j];
          if (RELU) v = fmaxf(v, 0.f);
          if (F16OUT)
            ((_Float16*)outv)[(size_t)row * DD + col] = (_Float16)v;
          else
            ((float*)outv)[(size_t)row * DD + col] = v;
        }
      }
    }
  }
}

// ---------------- gather disease rows (fp32 hbp) + scatter f16 into hbs ----
__global__ __launch_bounds__(256) void gather2_k(const float* __restrict__ h2,
    const int* __restrict__ bli, const int* __restrict__ mri,
    float* __restrict__ hbp, _Float16* __restrict__ hbs, int nd) {
  int gid = blockIdx.x * 256 + threadIdx.x;
  int i = gid >> 5, q = gid & 31;
  if (i < nd) {
    float4 v = *(const float4*)(h2 + (size_t)bli[i] * DD + q * 4);
    *(float4*)(hbp + (size_t)i * DD + q * 4) = v;
    h4 o = {(_Float16)v.x, (_Float16)v.y, (_Float16)v.z, (_Float16)v.w};
    *(h4*)(hbs + (size_t)mri[i] * DD + q * 4) = o;
  }
}

// ---------------- transpose hbs[KP][128] -> hbsT[128][KP] ----------------
__global__ __launch_bounds__(256) void transpose_k(const _Float16* __restrict__ hbs,
    _Float16* __restrict__ hbsT) {
  __shared__ _Float16 tile[64][72];
  int r0 = blockIdx.x * 64, c0 = blockIdx.y * 64;
  int t = threadIdx.x;
  int r = t >> 2, cs = (t & 3) * 16;
  *(h8*)&tile[r][cs]     = *(const h8*)(hbs + (size_t)(r0 + r) * DD + c0 + cs);
  *(h8*)&tile[r][cs + 8] = *(const h8*)(hbs + (size_t)(r0 + r) * DD + c0 + cs + 8);
  __syncthreads();
  int n = t >> 2, rs2 = (t & 3) * 16;
  h8 o0, o1;
#pragma unroll
  for (int j = 0; j < 8; ++j) {
    o0[j] = tile[rs2 + j][n];
    o1[j] = tile[rs2 + 8 + j][n];
  }
  *(h8*)(hbsT + (size_t)(c0 + n) * KP + r0 + rs2)     = o0;
  *(h8*)(hbsT + (size_t)(c0 + n) * KP + r0 + rs2 + 8) = o1;
}

// ---------------- sim MFMA GEMM: hs_part[ky] = simh[:, kchunk] @ hbsT^T ----
__global__ __launch_bounds__(256) void sim_mfma(const _Float16* __restrict__ simh,
    const _Float16* __restrict__ hbsT, float* __restrict__ hs_part, int nd) {
  __shared__ _Float16 Ab[2][64 * 64];
  __shared__ _Float16 Bb[2][128 * 64];
  const int t = threadIdx.x;
  const int lane = t & 63, w = t >> 6;
  const int row0 = blockIdx.x * 64;
  const int kb0 = blockIdx.y * (KP / KSPLIT);
  const int wm = w >> 1, wn = w & 1;
  const int lr = lane & 15, lg = lane >> 4;

  f4 acc[2][4];
#pragma unroll
  for (int mi = 0; mi < 2; ++mi)
#pragma unroll
    for (int ni = 0; ni < 4; ++ni) acc[mi][ni] = (f4){0.f, 0.f, 0.f, 0.f};

  const _Float16* pA[2];
  int ldsA[2];
#pragma unroll
  for (int j = 0; j < 2; ++j) {
    int q = j * 256 + w * 64 + lane;
    int row = q >> 3;
    int gck = (q & 7) ^ (row & 7);
    int m = row0 + row; if (m >= nd) m = nd - 1;
    pA[j] = simh + (size_t)m * KP + kb0 + gck * 8;
    ldsA[j] = (j * 256 + w * 64) * 8;
  }
  const _Float16* pB[4];
  int ldsB[4];
#pragma unroll
  for (int i = 0; i < 4; ++i) {
    int q = i * 256 + w * 64 + lane;
    int n = q >> 3;
    int gck = (q & 7) ^ (n & 7);
    pB[i] = hbsT + (size_t)n * KP + kb0 + gck * 8;
    ldsB[i] = (i * 256 + w * 64) * 8;
  }

  const int nsteps = (KP / KSPLIT) / 64;  // 8
#pragma unroll
  for (int j = 0; j < 2; ++j) gload16(pA[j], &Ab[0][ldsA[j]]);
#pragma unroll
  for (int i = 0; i < 4; ++i) gload16(pB[i], &Bb[0][ldsB[i]]);
  asm volatile("s_waitcnt vmcnt(0)" ::: "memory");
  __syncthreads();

  for (int ts = 0; ts < nsteps; ++ts) {
    const int cur = ts & 1;
    if (ts + 1 < nsteps) {
      const int kk = (ts + 1) * 64;
      const int nxt = cur ^ 1;
#pragma unroll
      for (int j = 0; j < 2; ++j) gload16(pA[j] + kk, &Ab[nxt][ldsA[j]]);
#pragma unroll
      for (int i = 0; i < 4; ++i) gload16(pB[i] + kk, &Bb[nxt][ldsB[i]]);
    }
#pragma unroll
    for (int s = 0; s < 2; ++s) {
      h8 af[2], bf[4];
#pragma unroll
      for (int mi = 0; mi < 2; ++mi) {
        int r = wm * 32 + mi * 16 + lr;
        af[mi] = *(const h8*)&Ab[cur][r * 64 + (((s * 4 + lg) ^ (r & 7)) << 3)];
      }
#pragma unroll
      for (int ni = 0; ni < 4; ++ni) {
        int n = wn * 64 + ni * 16 + lr;
        bf[ni] = *(const h8*)&Bb[cur][n * 64 + (((s * 4 + lg) ^ (n & 7)) << 3)];
      }
#pragma unroll
      for (int mi = 0; mi < 2; ++mi)
#pragma unroll
        for (int ni = 0; ni < 4; ++ni)
          acc[mi][ni] = __builtin_amdgcn_mfma_f32_16x16x32_f16(
              af[mi], bf[ni], acc[mi][ni], 0, 0, 0);
    }
    asm volatile("s_waitcnt vmcnt(0)" ::: "memory");
    __syncthreads();
  }

  float* dst = hs_part + (size_t)blockIdx.y * nd * DD;
#pragma unroll
  for (int mi = 0; mi < 2; ++mi) {
#pragma unroll
    for (int j = 0; j < 4; ++j) {
      int row = row0 + wm * 32 + mi * 16 + lg * 4 + j;
      if (row < nd) {
#pragma unroll
        for (int ni = 0; ni < 4; ++ni) {
          int col = wn * 64 + ni * 16 + lr;
          dst[(size_t)row * DD + col] = acc[mi][ni][j];
        }
      }
    }
  }
}

// ---------------- fused K-split reduce + final blend (deg from off) -------
__global__ __launch_bounds__(256) void reduce_final_k(
    const float* __restrict__ part, const float* __restrict__ hbp,
    const float* __restrict__ rs, const int* __restrict__ bli,
    const int* __restrict__ off, float* __restrict__ out, int nd,
    int NR, int E) {
  int gid = blockIdx.x * 256 + threadIdx.x;
  int i = gid >> 5, q = gid & 31;
  if (i < nd) {
    f4 s = (f4){0.f, 0.f, 0.f, 0.f};
#pragma unroll
    for (int p = 0; p < KSPLIT; ++p)
      s += *(const f4*)(part + (size_t)p * nd * DD + (size_t)i * DD + q * 4);
    int g = bli[i];
    int o0 = off[g * RR];
    int o1 = (g * RR + RR < NR) ? off[g * RR + RR] : E;
    float degf = (float)(o1 - o0);
    float cg = 0.7f * expf(-0.7f * degf) + 0.2f;
    float inv = 1.0f / rs[i];
    f4 bb = *(const f4*)(hbp + (size_t)i * DD + q * 4);
    f4 o;
#pragma unroll
    for (int j = 0; j < 4; ++j) o[j] = cg * (s[j] * inv) + (1.f - cg) * bb[j];
    *(f4*)(out + (size_t)g * DD + q * 4) = o;
  }
}

extern "C" void kernel_launch(void* const* d_in, const int* in_sizes, int n_in,
                              void* d_out, int out_size, void* d_ws, size_t ws_size,
                              hipStream_t stream) {
  const float* x   = (const float*)d_in[0];
  const float* sim = (const float*)d_in[1];
  const float* W1s = (const float*)d_in[2];
  const float* W1r = (const float*)d_in[3];
  const float* W2s = (const float*)d_in[4];
  const float* W2r = (const float*)d_in[5];
  const int* esrc  = (const int*)d_in[6];
  const int* edst  = (const int*)d_in[7];
  const int* etyp  = (const int*)d_in[8];
  const int* bli   = (const int*)d_in[9];
  const int* mri   = (const int*)d_in[10];
  const int N  = in_sizes[0] / DD;
  const int E  = in_sizes[6];
  const int ND = in_sizes[9];
  const int NR = N * RR;
  float* out = (float*)d_out;

  // workspace carve-up; cntp|maskf|hbs contiguous -> single memset
  char* w = (char*)d_ws;
  _Float16* msg  = (_Float16*)w; w += (size_t)NR * DD * sizeof(_Float16);   // 82 MB
  _Float16* xh   = (_Float16*)w; w += (size_t)N * DD * sizeof(_Float16);
  _Float16* h1h  = (_Float16*)w; w += (size_t)N * DD * sizeof(_Float16);
  _Float16* WT1  = (_Float16*)w; w += (size_t)DD * KK * sizeof(_Float16);
  _Float16* WT2  = (_Float16*)w; w += (size_t)DD * KK * sizeof(_Float16);
  _Float16* simh = (_Float16*)w; w += (size_t)ND * KP * sizeof(_Float16);
  _Float16* hbsT = (_Float16*)w; w += (size_t)DD * KP * sizeof(_Float16);
  float* hs_part = (float*)w; w += (size_t)KSPLIT * ND * DD * sizeof(float);
  float* hbp   = (float*)w; w += (size_t)ND * DD * sizeof(float);
  // ---- contiguous zero-init region ----
  unsigned* cntp = (unsigned*)w; w += (size_t)(NR / 2) * sizeof(unsigned);
  float* maskf   = (float*)w;    w += (size_t)KP * sizeof(float);
  _Float16* hbs  = (_Float16*)w; w += (size_t)KP * DD * sizeof(_Float16);
  // ----
  int* off  = (int*)w; w += (size_t)NR * sizeof(int);
  int* cur  = (int*)w; w += (size_t)NR * sizeof(int);
  int* eidx = (int*)w; w += (size_t)E * sizeof(int);
  int* bsum = (int*)w; w += 1024 * sizeof(int);
  float* rs = (float*)w; w += (size_t)ND * sizeof(float);

  const size_t zbytes = (size_t)(NR / 2) * sizeof(unsigned) +
                        (size_t)KP * sizeof(float) +
                        (size_t)KP * DD * sizeof(_Float16);
  hipMemsetAsync(cntp, 0, zbytes, stream);
  maskset_k<<<(ND + 255) / 256, 256, 0, stream>>>(mri, maskf, ND);

  // ---- split prep (diagnostic): count alone, then streaming roles ----
  const int n4x = N * DD / 4;
  const int bX = (n4x + 255) / 256;
  const int bW = (KK / 64) * (DD / 64);  // 36
  const int bC = (E + 255) / 256;
  count_k<<<bC, 256, 0, stream>>>(edst, etyp, cntp, E);
  stream_k<<<ND + bX + 2 * bW, 256, 0, stream>>>(
      sim, mri, maskf, simh, rs, ND, x, xh, n4x,
      W1s, W1r, WT1, W2s, W2r, WT2, bX, bW);

  // ---- CSR scan + fill ----
  int nblk = (NR + SCAN_CHUNK - 1) / SCAN_CHUNK;
  scan_a<<<nblk, 256, 0, stream>>>(cntp, off, bsum, NR);
  scan_b<<<1, 256, 0, stream>>>(bsum, nblk);
  scan_c<<<(NR + 255) / 256, 256, 0, stream>>>(off, bsum, cur, NR);
  fill_k<<<bC, 256, 0, stream>>>(esrc, edst, etyp, cur, eidx, E);

  // ---- layer 1 ----
  int aggBlk = (NR * 8 + 255) / 256;
  agg_k<<<aggBlk, 256, 0, stream>>>(xh, off, eidx, msg, NR, E);
  rgcn_mfma<true, true><<<(N + 63) / 64, 256, 0, stream>>>(xh, msg, WT1, h1h, N);

  // ---- layer 2 ----
  agg_k<<<aggBlk, 256, 0, stream>>>(h1h, off, eidx, msg, NR, E);
  rgcn_mfma<false, false><<<(N + 63) / 64, 256, 0, stream>>>(h1h, msg, WT2, out, N);

  // ---- similarity diffusion ----
  gather2_k<<<(ND * 32 + 255) / 256, 256, 0, stream>>>(out, bli, mri, hbp, hbs, ND);
  dim3 tgrid(KP / 64, DD / 64);
  transpose_k<<<tgrid, 256, 0, stream>>>(hbs, hbsT);
  dim3 sgrid((ND + 63) / 64, KSPLIT);
  sim_mfma<<<sgrid, 256, 0, stream>>>(simh, hbsT, hs_part, ND);
  reduce_final_k<<<(ND * 32 + 255) / 256, 256, 0, stream>>>(
      hs_part, hbp, rs, bli, off, out, ND, NR, E);
}

// Round 14
// 238.903 us; speedup vs baseline: 1.0716x; 1.0716x over previous
//
#include <hip/hip_runtime.h>
#include <hip/hip_bf16.h>

#define DD 128
#define RR 8
#define KK 1152      // RGCN composite K = 128 + 8*128
#define SCAN_CHUNK 2048
#define KSPLIT 8
#define KP 4096      // padded sim K

typedef _Float16 h8 __attribute__((ext_vector_type(8)));
typedef _Float16 h4 __attribute__((ext_vector_type(4)));
typedef float f4 __attribute__((ext_vector_type(4)));

__device__ __forceinline__ void gload16(const _Float16* g, _Float16* l) {
  __builtin_amdgcn_global_load_lds(
      (const __attribute__((address_space(1))) void*)g,
      (__attribute__((address_space(3))) void*)l, 16, 0, 0);
}

// ---------------- maskf scatter: maskf[mri[i]] = 1 ----------------
__global__ __launch_bounds__(256) void maskset_k(const int* __restrict__ mri,
    float* __restrict__ maskf, int nd) {
  int i = blockIdx.x * 256 + threadIdx.x;
  if (i < nd) maskf[mri[i]] = 1.0f;
}

// ---------------- sim row convert + fused rowsum (body) ----------------
__device__ __forceinline__ void convsim_body(const float* __restrict__ sim,
    const int* __restrict__ mri, const float* __restrict__ maskf,
    _Float16* __restrict__ simh, float* __restrict__ rs, int nd, int i,
    float* red) {
  const float* row = sim + (size_t)mri[i] * nd;
  float acc = 0.f;
  for (int c4 = threadIdx.x; c4 < KP / 4; c4 += 256) {
    int c = c4 * 4;
    float4 v = make_float4(0.f, 0.f, 0.f, 0.f);
    if (c < nd) {
      v = *(const float4*)(row + c);
      float4 mk = *(const float4*)(maskf + c);
      acc += v.x * mk.x + v.y * mk.y + v.z * mk.z + v.w * mk.w;
    }
    h4 o = {(_Float16)v.x, (_Float16)v.y, (_Float16)v.z, (_Float16)v.w};
    *(h4*)(simh + (size_t)i * KP + c) = o;
  }
  red[threadIdx.x] = acc;
  __syncthreads();
  for (int o = 128; o > 0; o >>= 1) {
    if (threadIdx.x < o) red[threadIdx.x] += red[threadIdx.x + o];
    __syncthreads();
  }
  if (threadIdx.x == 0) rs[i] = red[0] + 1e-9f;
}

// ---------------- combined: packed count (first) || convsim ----------------
__global__ __launch_bounds__(256) void cc_k(
    const int* __restrict__ edst, const int* __restrict__ etyp,
    unsigned* __restrict__ cntp, int E, int bC,
    const float* __restrict__ sim, const int* __restrict__ mri,
    const float* __restrict__ maskf, _Float16* __restrict__ simh,
    float* __restrict__ rs, int nd) {
  __shared__ float red[256];
  const int b = blockIdx.x, t = threadIdx.x;
  if (b < bC) {
    int i = b * 256 + t;
    if (i < E) {
      int seg = edst[i] * RR + etyp[i];
      atomicAdd(&cntp[seg >> 1], 1u << ((seg & 1) << 4));
    }
    return;
  }
  convsim_body(sim, mri, maskf, simh, rs, nd, b - bC, red);
}

// ---------------- 3-phase exclusive scan of packed cnt -> off -------------
__global__ __launch_bounds__(256) void scan_a(const unsigned* __restrict__ cntp,
    int* __restrict__ off, int* __restrict__ bsum, int n) {
  __shared__ int red[256];
  int base = blockIdx.x * SCAN_CHUNK + threadIdx.x * 8;
  int v[8];
  int s = 0;
#pragma unroll
  for (int i = 0; i < 8; ++i) {
    int idx = base + i;
    v[i] = s;
    int c = 0;
    if (idx < n) {
      unsigned word = cntp[idx >> 1];
      c = (word >> ((idx & 1) << 4)) & 0xFFFF;
    }
    s += c;
  }
  red[threadIdx.x] = s;
  __syncthreads();
  for (int o = 1; o < 256; o <<= 1) {
    int t = (threadIdx.x >= o) ? red[threadIdx.x - o] : 0;
    __syncthreads();
    red[threadIdx.x] += t;
    __syncthreads();
  }
  int pre = (threadIdx.x > 0) ? red[threadIdx.x - 1] : 0;
#pragma unroll
  for (int i = 0; i < 8; ++i) {
    int idx = base + i;
    if (idx < n) off[idx] = v[i] + pre;
  }
  if (threadIdx.x == 255) bsum[blockIdx.x] = red[255];
}

// merged scan_b + scan_c: every block redoes the tiny bsum scan in LDS
__global__ __launch_bounds__(256) void scan_bc(int* __restrict__ off,
    const int* __restrict__ bsum, int* __restrict__ cur, int n, int nblk) {
  __shared__ int pre[256];
  const int t = threadIdx.x;
  pre[t] = (t < nblk) ? bsum[t] : 0;
  __syncthreads();
  for (int o = 1; o < 256; o <<= 1) {
    int tv = (t >= o) ? pre[t - o] : 0;
    __syncthreads();
    pre[t] += tv;
    __syncthreads();
  }
  int i = blockIdx.x * 256 + t;
  if (i < n) {
    int c = i >> 11;  // SCAN_CHUNK = 2048
    int add = (c > 0) ? pre[c - 1] : 0;
    int val = off[i] + add;
    off[i] = val;
    cur[i] = val;
  }
}

// ---------------- transposed f16 weights via LDS tile (body) ----------------
__device__ __forceinline__ void convwT_body(const float* __restrict__ Ws,
    const float* __restrict__ Wr, _Float16* __restrict__ WT, int bid,
    _Float16 (*tile)[72]) {
  const int k0 = (bid % (KK / 64)) * 64, n0 = (bid / (KK / 64)) * 64;
  const int t = threadIdx.x;
  {
    int kr = t >> 2, c0 = (t & 3) * 16;
    int k = k0 + kr;
    const float* src = (k < DD) ? (Ws + (size_t)k * DD + n0 + c0)
                                : (Wr + (size_t)(k - DD) * DD + n0 + c0);
#pragma unroll
    for (int j = 0; j < 16; j += 4) {
      float4 v = *(const float4*)(src + j);
      tile[kr][c0 + j + 0] = (_Float16)v.x;
      tile[kr][c0 + j + 1] = (_Float16)v.y;
      tile[kr][c0 + j + 2] = (_Float16)v.z;
      tile[kr][c0 + j + 3] = (_Float16)v.w;
    }
  }
  __syncthreads();
  {
    int nr = t >> 2, ck = (t & 3) * 16;
    h8 o0, o1;
#pragma unroll
    for (int j = 0; j < 8; ++j) {
      o0[j] = tile[ck + j][nr];
      o1[j] = tile[ck + 8 + j][nr];
    }
    *(h8*)(WT + (size_t)(n0 + nr) * KK + k0 + ck) = o0;
    *(h8*)(WT + (size_t)(n0 + nr) * KK + k0 + ck + 8) = o1;
  }
}

// ---------------- combined: fill CSR (first) || convx || convwT x2 --------
__global__ __launch_bounds__(256) void fc_k(
    const int* __restrict__ esrc, const int* __restrict__ edst,
    const int* __restrict__ etyp, int* __restrict__ cur,
    int* __restrict__ eidx, int E, int bC,
    const float* __restrict__ x, _Float16* __restrict__ xh, int n4x, int bX,
    const float* __restrict__ W1s, const float* __restrict__ W1r,
    _Float16* __restrict__ WT1,
    const float* __restrict__ W2s, const float* __restrict__ W2r,
    _Float16* __restrict__ WT2, int bW) {
  __shared__ _Float16 tile[64][72];
  const int b = blockIdx.x, t = threadIdx.x;
  if (b < bC) {
    int e = b * 256 + t;
    if (e < E) {
      int seg = edst[e] * RR + etyp[e];
      int p = atomicAdd(&cur[seg], 1);
      eidx[p] = esrc[e];
    }
    return;
  }
  int b2 = b - bC;
  if (b2 < bX) {
    int i = b2 * 256 + t;
    if (i < n4x) {
      float4 v = *(const float4*)(x + (size_t)i * 4);
      h4 o = {(_Float16)v.x, (_Float16)v.y, (_Float16)v.z, (_Float16)v.w};
      *(h4*)(xh + (size_t)i * 4) = o;
    }
    return;
  }
  b2 -= bX;
  if (b2 < bW) {
    convwT_body(W1s, W1r, WT1, b2, tile);
    return;
  }
  b2 -= bW;
  convwT_body(W2s, W2r, WT2, b2, tile);
}

// ---------------- aggregation: 2 segments/thread, 8-deep load pipeline ----
__device__ __forceinline__ void agg_body2(const _Float16* __restrict__ h,
    const int* __restrict__ off, const int* __restrict__ eidx,
    _Float16* __restrict__ msg, int nseg, int E, int gid) {
  int pr = gid >> 4, q = gid & 15;
  int sg = pr * 2;
  if (sg >= nseg) return;
  int b0 = off[sg];
  int b1 = (sg + 1 < nseg) ? off[sg + 1] : E;
  int e1 = (sg + 2 < nseg) ? off[sg + 2] : E;
  int n0 = b1 - b0, n1 = e1 - b1;
  int eL = E - 1;
  int i00 = eidx[min(b0 + 0, eL)];
  int i01 = eidx[min(b0 + 1, eL)];
  int i02 = eidx[min(b0 + 2, eL)];
  int i03 = eidx[min(b0 + 3, eL)];
  int i10 = eidx[min(b1 + 0, eL)];
  int i11 = eidx[min(b1 + 1, eL)];
  int i12 = eidx[min(b1 + 2, eL)];
  int i13 = eidx[min(b1 + 3, eL)];
  h8 v00 = *(const h8*)(h + (size_t)i00 * DD + q * 8);
  h8 v01 = *(const h8*)(h + (size_t)i01 * DD + q * 8);
  h8 v02 = *(const h8*)(h + (size_t)i02 * DD + q * 8);
  h8 v03 = *(const h8*)(h + (size_t)i03 * DD + q * 8);
  h8 v10 = *(const h8*)(h + (size_t)i10 * DD + q * 8);
  h8 v11 = *(const h8*)(h + (size_t)i11 * DD + q * 8);
  h8 v12 = *(const h8*)(h + (size_t)i12 * DD + q * 8);
  h8 v13 = *(const h8*)(h + (size_t)i13 * DD + q * 8);
  float a0[8], a1[8];
#pragma unroll
  for (int j = 0; j < 8; ++j) { a0[j] = 0.f; a1[j] = 0.f; }
  if (n0 > 0) {
#pragma unroll
    for (int j = 0; j < 8; ++j) a0[j] = (float)v00[j];
    if (n0 > 1) {
#pragma unroll
      for (int j = 0; j < 8; ++j) a0[j] += (float)v01[j];
    }
    if (n0 > 2) {
#pragma unroll
      for (int j = 0; j < 8; ++j) a0[j] += (float)v02[j];
    }
    if (n0 > 3) {
#pragma unroll
      for (int j = 0; j < 8; ++j) a0[j] += (float)v03[j];
    }
    for (int i = b0 + 4; i < b1; ++i) {
      int s = eidx[i];
      h8 v = *(const h8*)(h + (size_t)s * DD + q * 8);
#pragma unroll
      for (int j = 0; j < 8; ++j) a0[j] += (float)v[j];
    }
  }
  if (n1 > 0) {
#pragma unroll
    for (int j = 0; j < 8; ++j) a1[j] = (float)v10[j];
    if (n1 > 1) {
#pragma unroll
      for (int j = 0; j < 8; ++j) a1[j] += (float)v11[j];
    }
    if (n1 > 2) {
#pragma unroll
      for (int j = 0; j < 8; ++j) a1[j] += (float)v12[j];
    }
    if (n1 > 3) {
#pragma unroll
      for (int j = 0; j < 8; ++j) a1[j] += (float)v13[j];
    }
    for (int i = b1 + 4; i < e1; ++i) {
      int s = eidx[i];
      h8 v = *(const h8*)(h + (size_t)s * DD + q * 8);
#pragma unroll
      for (int j = 0; j < 8; ++j) a1[j] += (float)v[j];
    }
  }
  float ic0 = (n0 > 0) ? 1.0f / (float)n0 : 0.0f;
  float ic1 = (n1 > 0) ? 1.0f / (float)n1 : 0.0f;
  h8 o0, o1;
#pragma unroll
  for (int j = 0; j < 8; ++j) {
    o0[j] = (_Float16)(a0[j] * ic0);
    o1[j] = (_Float16)(a1[j] * ic1);
  }
  *(h8*)(msg + (size_t)sg * DD + q * 8) = o0;
  if (sg + 1 < nseg)
    *(h8*)(msg + (size_t)(sg + 1) * DD + q * 8) = o1;
}

__global__ __launch_bounds__(256) void agg_k(const _Float16* __restrict__ h,
    const int* __restrict__ off, const int* __restrict__ eidx,
    _Float16* __restrict__ msg, int nseg, int E) {
  agg_body2(h, off, eidx, msg, nseg, E, blockIdx.x * 256 + threadIdx.x);
}

// ---------------- MFMA RGCN GEMM: out = [xh | msg] @ WT^T ----------------
template <bool RELU, bool F16OUT>
__global__ __launch_bounds__(256) void rgcn_mfma(const _Float16* __restrict__ xh,
    const _Float16* __restrict__ msg, const _Float16* __restrict__ WT,
    void* __restrict__ outv, int nN) {
  __shared__ _Float16 Ab[2][64 * 64];
  __shared__ _Float16 Bb[2][128 * 64];
  const int t = threadIdx.x;
  const int lane = t & 63, w = t >> 6;
  const int row0 = blockIdx.x * 64;
  const int wm = w >> 1, wn = w & 1;
  const int lr = lane & 15, lg = lane >> 4;

  f4 acc[2][4];
#pragma unroll
  for (int mi = 0; mi < 2; ++mi)
#pragma unroll
    for (int ni = 0; ni < 4; ++ni) acc[mi][ni] = (f4){0.f, 0.f, 0.f, 0.f};

  const _Float16* pxh[2];
  const _Float16* pmsg[2];
  int ldsA[2];
#pragma unroll
  for (int j = 0; j < 2; ++j) {
    int q = j * 256 + w * 64 + lane;
    int row = q >> 3;
    int gck = (q & 7) ^ (row & 7);
    int m = row0 + row; if (m >= nN) m = nN - 1;
    pxh[j] = xh + (size_t)m * DD + gck * 8;
    pmsg[j] = msg + (size_t)m * (RR * DD) + gck * 8;
    ldsA[j] = (j * 256 + w * 64) * 8;
  }
  const _Float16* pB[4];
  int ldsB[4];
#pragma unroll
  for (int i = 0; i < 4; ++i) {
    int q = i * 256 + w * 64 + lane;
    int n = q >> 3;
    int gck = (q & 7) ^ (n & 7);
    pB[i] = WT + (size_t)n * KK + gck * 8;
    ldsB[i] = (i * 256 + w * 64) * 8;
  }

  const int nsteps = KK / 64;  // 18
#pragma unroll
  for (int j = 0; j < 2; ++j) gload16(pxh[j], &Ab[0][ldsA[j]]);
#pragma unroll
  for (int i = 0; i < 4; ++i) gload16(pB[i], &Bb[0][ldsB[i]]);
  asm volatile("s_waitcnt vmcnt(0)" ::: "memory");
  __syncthreads();

  for (int ts = 0; ts < nsteps; ++ts) {
    const int cur = ts & 1;
    if (ts + 1 < nsteps) {
      const int kk = (ts + 1) * 64;
      const int nxt = cur ^ 1;
      if (kk < DD) {
#pragma unroll
        for (int j = 0; j < 2; ++j) gload16(pxh[j] + kk, &Ab[nxt][ldsA[j]]);
      } else {
#pragma unroll
        for (int j = 0; j < 2; ++j) gload16(pmsg[j] + (kk - DD), &Ab[nxt][ldsA[j]]);
      }
#pragma unroll
      for (int i = 0; i < 4; ++i) gload16(pB[i] + kk, &Bb[nxt][ldsB[i]]);
    }
#pragma unroll
    for (int s = 0; s < 2; ++s) {
      h8 af[2], bf[4];
#pragma unroll
      for (int mi = 0; mi < 2; ++mi) {
        int r = wm * 32 + mi * 16 + lr;
        af[mi] = *(const h8*)&Ab[cur][r * 64 + (((s * 4 + lg) ^ (r & 7)) << 3)];
      }
#pragma unroll
      for (int ni = 0; ni < 4; ++ni) {
        int n = wn * 64 + ni * 16 + lr;
        bf[ni] = *(const h8*)&Bb[cur][n * 64 + (((s * 4 + lg) ^ (n & 7)) << 3)];
      }
#pragma unroll
      for (int mi = 0; mi < 2; ++mi)
#pragma unroll
        for (int ni = 0; ni < 4; ++ni)
          acc[mi][ni] = __builtin_amdgcn_mfma_f32_16x16x32_f16(
              af[mi], bf[ni], acc[mi][ni], 0, 0, 0);
    }
    asm volatile("s_waitcnt vmcnt(0)" ::: "memory");
    __syncthreads();
  }

#pragma unroll
  for (int mi = 0; mi < 2; ++mi) {
#pragma unroll
    for (int j = 0; j < 4; ++j) {
      int row = row0 + wm * 32 + mi * 16 + lg * 4 + j;
      if (row < nN) {
#pragma unroll
        for (int ni = 0; ni < 4; ++ni) {
          int col = wn * 64 + ni * 16 + lr;
          float v = acc[mi][ni][j];
          if (RELU) v = fmaxf(v, 0.f);
          if (F16OUT)
            ((_Float16*)outv)[(size_t)row * DD + col] = (_Float16)v;
          else
            ((float*)outv)[(size_t)row * DD + col] = v;
        }
      }
    }
  }
}

// ---------------- gather disease rows (fp32 hbp) + scatter f16 into hbs ----
__global__ __launch_bounds__(256) void gather2_k(const float* __restrict__ h2,
    const int* __restrict__ bli, const int* __restrict__ mri,
    float* __restrict__ hbp, _Float16* __restrict__ hbs, int nd) {
  int gid = blockIdx.x * 256 + threadIdx.x;
  int i = gid >> 5, q = gid & 31;
  if (i < nd) {
    float4 v = *(const float4*)(h2 + (size_t)bli[i] * DD + q * 4);
    *(float4*)(hbp + (size_t)i * DD + q * 4) = v;
    h4 o = {(_Float16)v.x, (_Float16)v.y, (_Float16)v.z, (_Float16)v.w};
    *(h4*)(hbs + (size_t)mri[i] * DD + q * 4) = o;
  }
}

// ---------------- transpose hbs[KP][128] -> hbsT[128][KP] ----------------
__global__ __launch_bounds__(256) void transpose_k(const _Float16* __restrict__ hbs,
    _Float16* __restrict__ hbsT) {
  __shared__ _Float16 tile[64][72];
  int r0 = blockIdx.x * 64, c0 = blockIdx.y * 64;
  int t = threadIdx.x;
  int r = t >> 2, cs = (t & 3) * 16;
  *(h8*)&tile[r][cs]     = *(const h8*)(hbs + (size_t)(r0 + r) * DD + c0 + cs);
  *(h8*)&tile[r][cs + 8] = *(const h8*)(hbs + (size_t)(r0 + r) * DD + c0 + cs + 8);
  __syncthreads();
  int n = t >> 2, rs2 = (t & 3) * 16;
  h8 o0, o1;
#pragma unroll
  for (int j = 0; j < 8; ++j) {
    o0[j] = tile[rs2 + j][n];
    o1[j] = tile[rs2 + 8 + j][n];
  }
  *(h8*)(hbsT + (size_t)(c0 + n) * KP + r0 + rs2)     = o0;
  *(h8*)(hbsT + (size_t)(c0 + n) * KP + r0 + rs2 + 8) = o1;
}

// ---------------- sim MFMA GEMM: hs_part[ky] = simh[:, kchunk] @ hbsT^T ----
__global__ __launch_bounds__(256) void sim_mfma(const _Float16* __restrict__ simh,
    const _Float16* __restrict__ hbsT, float* __restrict__ hs_part, int nd) {
  __shared__ _Float16 Ab[2][64 * 64];
  __shared__ _Float16 Bb[2][128 * 64];
  const int t = threadIdx.x;
  const int lane = t & 63, w = t >> 6;
  const int row0 = blockIdx.x * 64;
  const int kb0 = blockIdx.y * (KP / KSPLIT);
  const int wm = w >> 1, wn = w & 1;
  const int lr = lane & 15, lg = lane >> 4;

  f4 acc[2][4];
#pragma unroll
  for (int mi = 0; mi < 2; ++mi)
#pragma unroll
    for (int ni = 0; ni < 4; ++ni) acc[mi][ni] = (f4){0.f, 0.f, 0.f, 0.f};

  const _Float16* pA[2];
  int ldsA[2];
#pragma unroll
  for (int j = 0; j < 2; ++j) {
    int q = j * 256 + w * 64 + lane;
    int row = q >> 3;
    int gck = (q & 7) ^ (row & 7);
    int m = row0 + row; if (m >= nd) m = nd - 1;
    pA[j] = simh + (size_t)m * KP + kb0 + gck * 8;
    ldsA[j] = (j * 256 + w * 64) * 8;
  }
  const _Float16* pB[4];
  int ldsB[4];
#pragma unroll
  for (int i = 0; i < 4; ++i) {
    int q = i * 256 + w * 64 + lane;
    int n = q >> 3;
    int gck = (q & 7) ^ (n & 7);
    pB[i] = hbsT + (size_t)n * KP + kb0 + gck * 8;
    ldsB[i] = (i * 256 + w * 64) * 8;
  }

  const int nsteps = (KP / KSPLIT) / 64;  // 8
#pragma unroll
  for (int j = 0; j < 2; ++j) gload16(pA[j], &Ab[0][ldsA[j]]);
#pragma unroll
  for (int i = 0; i < 4; ++i) gload16(pB[i], &Bb[0][ldsB[i]]);
  asm volatile("s_waitcnt vmcnt(0)" ::: "memory");
  __syncthreads();

  for (int ts = 0; ts < nsteps; ++ts) {
    const int cur = ts & 1;
    if (ts + 1 < nsteps) {
      const int kk = (ts + 1) * 64;
      const int nxt = cur ^ 1;
#pragma unroll
      for (int j = 0; j < 2; ++j) gload16(pA[j] + kk, &Ab[nxt][ldsA[j]]);
#pragma unroll
      for (int i = 0; i < 4; ++i) gload16(pB[i] + kk, &Bb[nxt][ldsB[i]]);
    }
#pragma unroll
    for (int s = 0; s < 2; ++s) {
      h8 af[2], bf[4];
#pragma unroll
      for (int mi = 0; mi < 2; ++mi) {
        int r = wm * 32 + mi * 16 + lr;
        af[mi] = *(const h8*)&Ab[cur][r * 64 + (((s * 4 + lg) ^ (r & 7)) << 3)];
      }
#pragma unroll
      for (int ni = 0; ni < 4; ++ni) {
        int n = wn * 64 + ni * 16 + lr;
        bf[ni] = *(const h8*)&Bb[cur][n * 64 + (((s * 4 + lg) ^ (n & 7)) << 3)];
      }
#pragma unroll
      for (int mi = 0; mi < 2; ++mi)
#pragma unroll
        for (int ni = 0; ni < 4; ++ni)
          acc[mi][ni] = __builtin_amdgcn_mfma_f32_16x16x32_f16(
              af[mi], bf[ni], acc[mi][ni], 0, 0, 0);
    }
    asm volatile("s_waitcnt vmcnt(0)" ::: "memory");
    __syncthreads();
  }

  float* dst = hs_part + (size_t)blockIdx.y * nd * DD;
#pragma unroll
  for (int mi = 0; mi < 2; ++mi) {
#pragma unroll
    for (int j = 0; j < 4; ++j) {
      int row = row0 + wm * 32 + mi * 16 + lg * 4 + j;
      if (row < nd) {
#pragma unroll
        for (int ni = 0; ni < 4; ++ni) {
          int col = wn * 64 + ni * 16 + lr;
          dst[(size_t)row * DD + col] = acc[mi][ni][j];
        }
      }
    }
  }
}

// ---------------- fused K-split reduce + final blend (deg from off) -------
__global__ __launch_bounds__(256) void reduce_final_k(
    const float* __restrict__ part, const float* __restrict__ hbp,
    const float* __restrict__ rs, const int* __restrict__ bli,
    const int* __restrict__ off, float* __restrict__ out, int nd,
    int NR, int E) {
  int gid = blockIdx.x * 256 + threadIdx.x;
  int i = gid >> 5, q = gid & 31;
  if (i < nd) {
    f4 s = (f4){0.f, 0.f, 0.f, 0.f};
#pragma unroll
    for (int p = 0; p < KSPLIT; ++p)
      s += *(const f4*)(part + (size_t)p * nd * DD + (size_t)i * DD + q * 4);
    int g = bli[i];
    int o0 = off[g * RR];
    int o1 = (g * RR + RR < NR) ? off[g * RR + RR] : E;
    float degf = (float)(o1 - o0);
    float cg = 0.7f * expf(-0.7f * degf) + 0.2f;
    float inv = 1.0f / rs[i];
    f4 bb = *(const f4*)(hbp + (size_t)i * DD + q * 4);
    f4 o;
#pragma unroll
    for (int j = 0; j < 4; ++j) o[j] = cg * (s[j] * inv) + (1.f - cg) * bb[j];
    *(f4*)(out + (size_t)g * DD + q * 4) = o;
  }
}

extern "C" void kernel_launch(void* const* d_in, const int* in_sizes, int n_in,
                              void* d_out, int out_size, void* d_ws, size_t ws_size,
                              hipStream_t stream) {
  const float* x   = (const float*)d_in[0];
  const float* sim = (const float*)d_in[1];
  const float* W1s = (const float*)d_in[2];
  const float* W1r = (const float*)d_in[3];
  const float* W2s = (const float*)d_in[4];
  const float* W2r = (const float*)d_in[5];
  const int* esrc  = (const int*)d_in[6];
  const int* edst  = (const int*)d_in[7];
  const int* etyp  = (const int*)d_in[8];
  const int* bli   = (const int*)d_in[9];
  const int* mri   = (const int*)d_in[10];
  const int N  = in_sizes[0] / DD;
  const int E  = in_sizes[6];
  const int ND = in_sizes[9];
  const int NR = N * RR;
  float* out = (float*)d_out;

  // workspace carve-up; cntp|maskf|hbs contiguous -> single memset
  char* w = (char*)d_ws;
  _Float16* msg  = (_Float16*)w; w += (size_t)NR * DD * sizeof(_Float16);   // 82 MB
  _Float16* xh   = (_Float16*)w; w += (size_t)N * DD * sizeof(_Float16);
  _Float16* h1h  = (_Float16*)w; w += (size_t)N * DD * sizeof(_Float16);
  _Float16* WT1  = (_Float16*)w; w += (size_t)DD * KK * sizeof(_Float16);
  _Float16* WT2  = (_Float16*)w; w += (size_t)DD * KK * sizeof(_Float16);
  _Float16* simh = (_Float16*)w; w += (size_t)ND * KP * sizeof(_Float16);
  _Float16* hbsT = (_Float16*)w; w += (size_t)DD * KP * sizeof(_Float16);
  float* hs_part = (float*)w; w += (size_t)KSPLIT * ND * DD * sizeof(float);
  float* hbp   = (float*)w; w += (size_t)ND * DD * sizeof(float);
  // ---- contiguous zero-init region ----
  unsigned* cntp = (unsigned*)w; w += (size_t)(NR / 2) * sizeof(unsigned);
  float* maskf   = (float*)w;    w += (size_t)KP * sizeof(float);
  _Float16* hbs  = (_Float16*)w; w += (size_t)KP * DD * sizeof(_Float16);
  // ----
  int* off  = (int*)w; w += (size_t)NR * sizeof(int);
  int* cur  = (int*)w; w += (size_t)NR * sizeof(int);
  int* eidx = (int*)w; w += (size_t)E * sizeof(int);
  int* bsum = (int*)w; w += 1024 * sizeof(int);
  float* rs = (float*)w; w += (size_t)ND * sizeof(float);

  const size_t zbytes = (size_t)(NR / 2) * sizeof(unsigned) +
                        (size_t)KP * sizeof(float) +
                        (size_t)KP * DD * sizeof(_Float16);
  hipMemsetAsync(cntp, 0, zbytes, stream);
  maskset_k<<<(ND + 255) / 256, 256, 0, stream>>>(mri, maskf, ND);

  // ---- combined count || convsim ----
  const int bC = (E + 255) / 256;
  cc_k<<<bC + ND, 256, 0, stream>>>(edst, etyp, cntp, E, bC,
                                    sim, mri, maskf, simh, rs, ND);

  // ---- CSR scan ----
  int nblk = (NR + SCAN_CHUNK - 1) / SCAN_CHUNK;  // 157
  scan_a<<<nblk, 256, 0, stream>>>(cntp, off, bsum, NR);
  scan_bc<<<(NR + 255) / 256, 256, 0, stream>>>(off, bsum, cur, NR, nblk);

  // ---- combined fill || convx || convwT x2 ----
  const int n4x = N * DD / 4;
  const int bX = (n4x + 255) / 256;
  const int bW = (KK / 64) * (DD / 64);  // 36
  fc_k<<<bC + bX + 2 * bW, 256, 0, stream>>>(
      esrc, edst, etyp, cur, eidx, E, bC,
      x, xh, n4x, bX, W1s, W1r, WT1, W2s, W2r, WT2, bW);

  // ---- layer 1 ----
  int aggBlk = (NR * 8 + 255) / 256;
  agg_k<<<aggBlk, 256, 0, stream>>>(xh, off, eidx, msg, NR, E);
  rgcn_mfma<true, true><<<(N + 63) / 64, 256, 0, stream>>>(xh, msg, WT1, h1h, N);

  // ---- layer 2 ----
  agg_k<<<aggBlk, 256, 0, stream>>>(h1h, off, eidx, msg, NR, E);
  rgcn_mfma<false, false><<<(N + 63) / 64, 256, 0, stream>>>(h1h, msg, WT2, out, N);

  // ---- similarity diffusion ----
  gather2_k<<<(ND * 32 + 255) / 256, 256, 0, stream>>>(out, bli, mri, hbp, hbs, ND);
  dim3 tgrid(KP / 64, DD / 64);
  transpose_k<<<tgrid, 256, 0, stream>>>(hbs, hbsT);
  dim3 sgrid((ND + 63) / 64, KSPLIT);
  sim_mfma<<<sgrid, 256, 0, stream>>>(simh, hbsT, hs_part, ND);
  reduce_final_k<<<(ND * 32 + 255) / 256, 256, 0, stream>>>(
      hs_part, hbp, rs, bli, off, out, ND, NR, E);
}